// Round 12
// baseline (413.944 us; speedup 1.0000x reference)
//
#include <hip/hip_runtime.h>

// DarcyLoss: B=4096, C=2, H=W=64. Inputs (f32): model_out, target, x0_hat [B,2,64,64], var [B].
// loss = mean((mo-tg)^2) + mean_b( min(0.5*r_b^2/var_b, 27.6310211159) )
// r_b = (sum(eq0)+sum(bc)) / (64*64*3);  source f_s sums to 0 -> omitted.
//
// R12 = R11's float2 row-pair stencil, split across TWO waves per batch
// (8192 waves -> 32 waves/CU occupancy cap; doubles memory streams/CU).
// Block-iter t covers rows {2t,2t+1}: lanes 0..31 even row, 32..63 odd row,
// 2 cols/lane. half=0: t=0..15 (+block16 halo), chunks 0..15.
// half=1: t=16..31 (+block15 halo), chunks 16..31.
// t0 = half*16 == 0 mod 8 -> window slot math identical for both halves.
// Vertical neighbors: __shfl_xor 32 with carried swizzles; horizontal: lane+-1.
// Partial residual sums combined BEFORE square/clamp in final kernel (exact).
// No LDS, no barriers, no atomics.

#define NB 4096
#define HW 4096          // 64*64
#define CHW 8192         // 2*64*64

typedef float vf4 __attribute__((ext_vector_type(4)));
typedef float vf2 __attribute__((ext_vector_type(2)));

__device__ __forceinline__ vf2 swz32(vf2 v) {          // lane ^ 32
    vf2 r; r.x = __shfl_xor(v.x, 32); r.y = __shfl_xor(v.y, 32); return r;
}
__device__ __forceinline__ vf2 shl1(vf2 v, int lane) { // from lane-1
    vf2 r; const int s = (lane + 63) & 63;
    r.x = __shfl(v.x, s); r.y = __shfl(v.y, s); return r;
}
__device__ __forceinline__ vf2 shr1(vf2 v, int lane) { // from lane+1
    vf2 r; const int s = (lane + 1) & 63;
    r.x = __shfl(v.x, s); r.y = __shfl(v.y, s); return r;
}
__device__ __forceinline__ vf2 sel2(bool c, vf2 a, vf2 b) {
    vf2 r; r.x = c ? a.x : b.x; r.y = c ? a.y : b.y; return r;
}

__global__ __launch_bounds__(256, 8) void darcy_wave_kernel(
    const float* __restrict__ mo, const float* __restrict__ tg,
    const float* __restrict__ x0, float* __restrict__ ws_r, float* __restrict__ ws_d)
{
    constexpr float INV2D = 31.5f;            // 1/(2D), D=1/63
    constexpr float INVD2 = 3969.0f;          // 1/D^2

    const int wv   = threadIdx.x >> 6;
    const int lane = threadIdx.x & 63;
    const int half = wv & 1;
    const int b    = blockIdx.x * 2 + (wv >> 1);
    const int t0   = half << 4;               // 0 or 16
    const bool h   = (lane >> 5) != 0;        // false: even row, true: odd row
    const bool jlo = ((lane & 31) == 0);      // cell a is col 0
    const bool jhi = ((lane & 31) == 31);     // cell b is col 63

    const vf2* p2 = (const vf2*)(x0 + (size_t)b * CHW);   // 2048 vf2 (p plane)
    const vf2* q2 = p2 + 2048;                            // perm plane
    const vf4* m4 = (const vf4*)(mo + (size_t)b * CHW);   // 2048 f4
    const vf4* g4 = (const vf4*)(tg + (size_t)b * CHW);

    float rsum = 0.0f, dsum = 0.0f;

    // ---- 8-slot vf2 row-pair pipeline; preload blocks t0..t0+5 ----
    vf2 pw[8], qw[8];
    #pragma unroll
    for (int k = 0; k < 6; ++k) {
        pw[k] = p2[((t0 + k) << 6) + lane];
        qw[k] = q2[((t0 + k) << 6) + lane];
    }

    // swizzle carries; half=1 seeds s_prv from halo block 15 (row 31)
    vf2 spc = swz32(pw[0]), sqc = swz32(qw[0]);
    vf2 spp, sqp;
    if (half) {
        spp = swz32(p2[(15 << 6) + lane]);
        sqp = swz32(q2[(15 << 6) + lane]);
    } else {
        spp = spc; sqp = sqc;                 // garbage-safe: masked at s=0
    }

    const int pfmax = half ? 9 : 10;          // last s that prefetches (half0 halo: block 16)

    #pragma unroll
    for (int s = 0; s < 16; ++s) {
        // prefetch block t0+s+6 (half0: through block 16; half1: through 31)
        if (s <= pfmax) {
            pw[(s + 6) & 7] = p2[((t0 + s + 6) << 6) + lane];
            qw[(s + 6) & 7] = q2[((t0 + s + 6) << 6) + lane];
        }
        // fused data-loss chunk t0+s (nontemporal: zero reuse)
        {
            vf4 a = __builtin_nontemporal_load(m4 + ((t0 + s) << 6) + lane);
            vf4 g = __builtin_nontemporal_load(g4 + ((t0 + s) << 6) + lane);
            vf4 e = a - g;
            dsum += e.x * e.x + e.y * e.y + e.z * e.z + e.w * e.w;
        }

        const vf2 pc  = pw[s & 7],       qc  = qw[s & 7];
        const vf2 pnx = pw[(s + 1) & 7], qnx = qw[(s + 1) & 7]; // garbage at half1 s=15 (masked)
        const vf2 spn = swz32(pnx), sqn = swz32(qnx);

        // vertical neighbors (rows r+-1)
        const vf2 upP = sel2(h, spn, spc), dnP = sel2(h, spc, spp);
        const vf2 upQ = sel2(h, sqn, sqc), dnQ = sel2(h, sqc, sqp);

        vf2 pd0  = (upP - dnP) * INV2D;
        vf2 pd00 = (upP - 2.0f * pc + dnP) * INVD2;
        vf2 qd0  = (upQ - dnQ) * INV2D;

        if (half == 0 && s == 0) {   // row 0 one-sided (even-row lanes)
            vf2 od0  = (-3.0f * pc + 4.0f * spc - pnx) * INV2D;
            vf2 od00 = (2.0f * pc - 5.0f * spc + 4.0f * pnx - spn) * INVD2;
            vf2 oq0  = (-3.0f * qc + 4.0f * sqc - qnx) * INV2D;
            pd0 = sel2(!h, od0, pd0); pd00 = sel2(!h, od00, pd00); qd0 = sel2(!h, oq0, qd0);
        }
        if (half == 1 && s == 15) {  // row 63 one-sided (odd-row lanes)
            const vf2 pprv = pw[(s - 1) & 7], qprv = qw[(s - 1) & 7];   // block 30
            vf2 od0  = (3.0f * pc - 4.0f * spc + pprv) * INV2D;
            vf2 od00 = (2.0f * pc - 5.0f * spc + 4.0f * pprv - spp) * INVD2;
            vf2 oq0  = (3.0f * qc - 4.0f * sqc + qprv) * INV2D;
            pd0 = sel2(h, od0, pd0); pd00 = sel2(h, od00, pd00); qd0 = sel2(h, oq0, qd0);
        }

        // horizontal neighbors
        const vf2 l2p = shl1(pc, lane), r2p = shr1(pc, lane);
        const vf2 l2q = shl1(qc, lane), r2q = shr1(qc, lane);

        // cell a (col c0): interior left=l2p.y, right=pc.y; j=0 one-sided
        float pd1a  = (pc.y - l2p.y) * INV2D;
        float pd11a = (pc.y - 2.0f * pc.x + l2p.y) * INVD2;
        float qd1a  = (qc.y - l2q.y) * INV2D;
        if (jlo) {
            pd1a  = (-3.0f * pc.x + 4.0f * pc.y - r2p.x) * INV2D;
            pd11a = (2.0f * pc.x - 5.0f * pc.y + 4.0f * r2p.x - r2p.y) * INVD2;
            qd1a  = (-3.0f * qc.x + 4.0f * qc.y - r2q.x) * INV2D;
        }
        // cell b (col c0+1): interior left=pc.x, right=r2p.x; j=63 one-sided
        float pd1b  = (r2p.x - pc.x) * INV2D;
        float pd11b = (r2p.x - 2.0f * pc.y + pc.x) * INVD2;
        float qd1b  = (r2q.x - qc.x) * INV2D;
        if (jhi) {
            pd1b  = (3.0f * pc.y - 4.0f * pc.x + l2p.y) * INV2D;
            pd11b = (2.0f * pc.y - 5.0f * pc.x + 4.0f * l2p.y - l2p.x) * INVD2;
            qd1b  = (3.0f * qc.y - 4.0f * qc.x + l2q.y) * INV2D;
        }

        // eq0 = -(perm*(pd00+pd11) + qd0*pd0 + qd1*pd1), two cells
        rsum -= qc.x * (pd00.x + pd11a) + qd0.x * pd0.x + qd1a * pd1a;
        rsum -= qc.y * (pd00.y + pd11b) + qd0.y * pd0.y + qd1b * pd1b;

        // boundary-condition terms
        if (half == 0 && s == 0)  rsum -= (!h) ? (pd0.x + pd0.y) : 0.0f;  // i=0
        if (half == 1 && s == 15) rsum += h    ? (pd0.x + pd0.y) : 0.0f;  // i=63
        rsum += jlo ? pd1a : 0.0f;                                        // j=0
        rsum -= jhi ? pd1b : 0.0f;                                        // j=63

        // rotate swizzle carries
        spp = spc; spc = spn; sqp = sqc; sqc = sqn;
    }

    // ---- per-wave reduction; write partials ----
    #pragma unroll
    for (int off = 32; off > 0; off >>= 1) {
        rsum += __shfl_down(rsum, off);
        dsum += __shfl_down(dsum, off);
    }
    if (lane == 0) {
        ws_r[half * NB + b] = rsum;
        ws_d[half * NB + b] = dsum;
    }
}

__global__ __launch_bounds__(256) void darcy_final_kernel(
    const float* __restrict__ ws_r, const float* __restrict__ ws_d,
    const float* __restrict__ var, float* __restrict__ out)
{
    constexpr float CLAMP = 27.6310211159f;
    const int t = threadIdx.x;
    double rs = 0.0, ds = 0.0;
    for (int i = t; i < NB; i += 256) {
        const float rb = ws_r[i] + ws_r[NB + i];
        const float r  = rb * (1.0f / (64.0f * 64.0f * 3.0f));
        float res = 0.5f * r * r / var[i];
        rs += (double)fminf(res, CLAMP);
        ds += (double)(ws_d[i] + ws_d[NB + i]);
    }
    #pragma unroll
    for (int off = 32; off > 0; off >>= 1) {
        rs += __shfl_down(rs, off);
        ds += __shfl_down(ds, off);
    }
    __shared__ double red[8];
    const int wid = t >> 6, lane = t & 63;
    if (lane == 0) { red[wid] = rs; red[4 + wid] = ds; }
    __syncthreads();
    if (t == 0) {
        const double R  = red[0] + red[1] + red[2] + red[3];
        const double Dd = red[4] + red[5] + red[6] + red[7];
        out[0] = (float)(Dd / ((double)NB * (double)CHW) + R / (double)NB);
    }
}

extern "C" void kernel_launch(void* const* d_in, const int* in_sizes, int n_in,
                              void* d_out, int out_size, void* d_ws, size_t ws_size,
                              hipStream_t stream) {
    const float* mo  = (const float*)d_in[0];
    const float* tg  = (const float*)d_in[1];
    const float* x0  = (const float*)d_in[2];
    const float* var = (const float*)d_in[3];
    float* out = (float*)d_out;

    float* ws_r = (float*)d_ws;            // 2*NB floats
    float* ws_d = ws_r + 2 * NB;           // 2*NB floats

    darcy_wave_kernel<<<NB / 2, 256, 0, stream>>>(mo, tg, x0, ws_r, ws_d);
    darcy_final_kernel<<<1, 256, 0, stream>>>(ws_r, ws_d, var, out);
}

// Round 13
// 288.409 us; speedup vs baseline: 1.4353x; 1.4353x over previous
//
#include <hip/hip_runtime.h>

// DarcyLoss: B=4096, C=2, H=W=64. Inputs (f32): model_out, target, x0_hat [B,2,64,64], var [B].
// loss = mean((mo-tg)^2) + mean_b( min(0.5*r_b^2/var_b, 27.6310211159) )
// r_b = (sum(eq0)+sum(bc)) / (64*64*3);  source f_s sums to 0 -> omitted.
//
// R13 = R12 with __launch_bounds__(256,4): R12's (256,8) capped VGPR at 64 and
// forced the vf2 window into scratch (WRITE_SIZE 780 MB, 414 us). With the
// 128-VGPR budget the window stays in registers; VGPR ~<=56 still permits
// 8 waves/EU, so the 8192-wave grid reaches ~32 waves/CU naturally.
// Structure: two waves per batch, float2 row-pair stencil, 8-slot pipeline,
// __shfl_xor(32) verticals with carried swizzles, lane+-1 horizontals,
// fused nontemporal mo/tg streaming. Partials combined before square/clamp.

#define NB 4096
#define HW 4096          // 64*64
#define CHW 8192         // 2*64*64

typedef float vf4 __attribute__((ext_vector_type(4)));
typedef float vf2 __attribute__((ext_vector_type(2)));

__device__ __forceinline__ vf2 swz32(vf2 v) {          // lane ^ 32
    vf2 r; r.x = __shfl_xor(v.x, 32); r.y = __shfl_xor(v.y, 32); return r;
}
__device__ __forceinline__ vf2 shl1(vf2 v, int lane) { // from lane-1
    vf2 r; const int s = (lane + 63) & 63;
    r.x = __shfl(v.x, s); r.y = __shfl(v.y, s); return r;
}
__device__ __forceinline__ vf2 shr1(vf2 v, int lane) { // from lane+1
    vf2 r; const int s = (lane + 1) & 63;
    r.x = __shfl(v.x, s); r.y = __shfl(v.y, s); return r;
}
__device__ __forceinline__ vf2 sel2(bool c, vf2 a, vf2 b) {
    vf2 r; r.x = c ? a.x : b.x; r.y = c ? a.y : b.y; return r;
}

__global__ __launch_bounds__(256, 4) void darcy_wave_kernel(
    const float* __restrict__ mo, const float* __restrict__ tg,
    const float* __restrict__ x0, float* __restrict__ ws_r, float* __restrict__ ws_d)
{
    constexpr float INV2D = 31.5f;            // 1/(2D), D=1/63
    constexpr float INVD2 = 3969.0f;          // 1/D^2

    const int wv   = threadIdx.x >> 6;
    const int lane = threadIdx.x & 63;
    const int half = wv & 1;
    const int b    = blockIdx.x * 2 + (wv >> 1);
    const int t0   = half << 4;               // 0 or 16
    const bool h   = (lane >> 5) != 0;        // false: even row, true: odd row
    const bool jlo = ((lane & 31) == 0);      // cell a is col 0
    const bool jhi = ((lane & 31) == 31);     // cell b is col 63

    const vf2* p2 = (const vf2*)(x0 + (size_t)b * CHW);   // 2048 vf2 (p plane)
    const vf2* q2 = p2 + 2048;                            // perm plane
    const vf4* m4 = (const vf4*)(mo + (size_t)b * CHW);   // 2048 f4
    const vf4* g4 = (const vf4*)(tg + (size_t)b * CHW);

    float rsum = 0.0f, dsum = 0.0f;

    // ---- 8-slot vf2 row-pair pipeline; preload blocks t0..t0+5 ----
    vf2 pw[8], qw[8];
    #pragma unroll
    for (int k = 0; k < 6; ++k) {
        pw[k] = p2[((t0 + k) << 6) + lane];
        qw[k] = q2[((t0 + k) << 6) + lane];
    }

    // swizzle carries; half=1 seeds s_prv from halo block 15 (row 31)
    vf2 spc = swz32(pw[0]), sqc = swz32(qw[0]);
    vf2 spp, sqp;
    if (half) {
        spp = swz32(p2[(15 << 6) + lane]);
        sqp = swz32(q2[(15 << 6) + lane]);
    } else {
        spp = spc; sqp = sqc;                 // garbage-safe: masked at s=0
    }

    const int pfmax = half ? 9 : 10;          // last s that prefetches (half0 halo: block 16)

    #pragma unroll
    for (int s = 0; s < 16; ++s) {
        // prefetch block t0+s+6 (half0: through block 16; half1: through 31)
        if (s <= pfmax) {
            pw[(s + 6) & 7] = p2[((t0 + s + 6) << 6) + lane];
            qw[(s + 6) & 7] = q2[((t0 + s + 6) << 6) + lane];
        }
        // fused data-loss chunk t0+s (nontemporal: zero reuse)
        {
            vf4 a = __builtin_nontemporal_load(m4 + ((t0 + s) << 6) + lane);
            vf4 g = __builtin_nontemporal_load(g4 + ((t0 + s) << 6) + lane);
            vf4 e = a - g;
            dsum += e.x * e.x + e.y * e.y + e.z * e.z + e.w * e.w;
        }

        const vf2 pc  = pw[s & 7],       qc  = qw[s & 7];
        const vf2 pnx = pw[(s + 1) & 7], qnx = qw[(s + 1) & 7]; // garbage at half1 s=15 (masked)
        const vf2 spn = swz32(pnx), sqn = swz32(qnx);

        // vertical neighbors (rows r+-1)
        const vf2 upP = sel2(h, spn, spc), dnP = sel2(h, spc, spp);
        const vf2 upQ = sel2(h, sqn, sqc), dnQ = sel2(h, sqc, sqp);

        vf2 pd0  = (upP - dnP) * INV2D;
        vf2 pd00 = (upP - 2.0f * pc + dnP) * INVD2;
        vf2 qd0  = (upQ - dnQ) * INV2D;

        if (half == 0 && s == 0) {   // row 0 one-sided (even-row lanes)
            vf2 od0  = (-3.0f * pc + 4.0f * spc - pnx) * INV2D;
            vf2 od00 = (2.0f * pc - 5.0f * spc + 4.0f * pnx - spn) * INVD2;
            vf2 oq0  = (-3.0f * qc + 4.0f * sqc - qnx) * INV2D;
            pd0 = sel2(!h, od0, pd0); pd00 = sel2(!h, od00, pd00); qd0 = sel2(!h, oq0, qd0);
        }
        if (half == 1 && s == 15) {  // row 63 one-sided (odd-row lanes)
            const vf2 pprv = pw[(s - 1) & 7], qprv = qw[(s - 1) & 7];   // block 30
            vf2 od0  = (3.0f * pc - 4.0f * spc + pprv) * INV2D;
            vf2 od00 = (2.0f * pc - 5.0f * spc + 4.0f * pprv - spp) * INVD2;
            vf2 oq0  = (3.0f * qc - 4.0f * sqc + qprv) * INV2D;
            pd0 = sel2(h, od0, pd0); pd00 = sel2(h, od00, pd00); qd0 = sel2(h, oq0, qd0);
        }

        // horizontal neighbors
        const vf2 l2p = shl1(pc, lane), r2p = shr1(pc, lane);
        const vf2 l2q = shl1(qc, lane), r2q = shr1(qc, lane);

        // cell a (col c0): interior left=l2p.y, right=pc.y; j=0 one-sided
        float pd1a  = (pc.y - l2p.y) * INV2D;
        float pd11a = (pc.y - 2.0f * pc.x + l2p.y) * INVD2;
        float qd1a  = (qc.y - l2q.y) * INV2D;
        if (jlo) {
            pd1a  = (-3.0f * pc.x + 4.0f * pc.y - r2p.x) * INV2D;
            pd11a = (2.0f * pc.x - 5.0f * pc.y + 4.0f * r2p.x - r2p.y) * INVD2;
            qd1a  = (-3.0f * qc.x + 4.0f * qc.y - r2q.x) * INV2D;
        }
        // cell b (col c0+1): interior left=pc.x, right=r2p.x; j=63 one-sided
        float pd1b  = (r2p.x - pc.x) * INV2D;
        float pd11b = (r2p.x - 2.0f * pc.y + pc.x) * INVD2;
        float qd1b  = (r2q.x - qc.x) * INV2D;
        if (jhi) {
            pd1b  = (3.0f * pc.y - 4.0f * pc.x + l2p.y) * INV2D;
            pd11b = (2.0f * pc.y - 5.0f * pc.x + 4.0f * l2p.y - l2p.x) * INVD2;
            qd1b  = (3.0f * qc.y - 4.0f * qc.x + l2q.y) * INV2D;
        }

        // eq0 = -(perm*(pd00+pd11) + qd0*pd0 + qd1*pd1), two cells
        rsum -= qc.x * (pd00.x + pd11a) + qd0.x * pd0.x + qd1a * pd1a;
        rsum -= qc.y * (pd00.y + pd11b) + qd0.y * pd0.y + qd1b * pd1b;

        // boundary-condition terms
        if (half == 0 && s == 0)  rsum -= (!h) ? (pd0.x + pd0.y) : 0.0f;  // i=0
        if (half == 1 && s == 15) rsum += h    ? (pd0.x + pd0.y) : 0.0f;  // i=63
        rsum += jlo ? pd1a : 0.0f;                                        // j=0
        rsum -= jhi ? pd1b : 0.0f;                                        // j=63

        // rotate swizzle carries
        spp = spc; spc = spn; sqp = sqc; sqc = sqn;
    }

    // ---- per-wave reduction; write partials ----
    #pragma unroll
    for (int off = 32; off > 0; off >>= 1) {
        rsum += __shfl_down(rsum, off);
        dsum += __shfl_down(dsum, off);
    }
    if (lane == 0) {
        ws_r[half * NB + b] = rsum;
        ws_d[half * NB + b] = dsum;
    }
}

__global__ __launch_bounds__(256) void darcy_final_kernel(
    const float* __restrict__ ws_r, const float* __restrict__ ws_d,
    const float* __restrict__ var, float* __restrict__ out)
{
    constexpr float CLAMP = 27.6310211159f;
    const int t = threadIdx.x;
    double rs = 0.0, ds = 0.0;
    for (int i = t; i < NB; i += 256) {
        const float rb = ws_r[i] + ws_r[NB + i];
        const float r  = rb * (1.0f / (64.0f * 64.0f * 3.0f));
        float res = 0.5f * r * r / var[i];
        rs += (double)fminf(res, CLAMP);
        ds += (double)(ws_d[i] + ws_d[NB + i]);
    }
    #pragma unroll
    for (int off = 32; off > 0; off >>= 1) {
        rs += __shfl_down(rs, off);
        ds += __shfl_down(ds, off);
    }
    __shared__ double red[8];
    const int wid = t >> 6, lane = t & 63;
    if (lane == 0) { red[wid] = rs; red[4 + wid] = ds; }
    __syncthreads();
    if (t == 0) {
        const double R  = red[0] + red[1] + red[2] + red[3];
        const double Dd = red[4] + red[5] + red[6] + red[7];
        out[0] = (float)(Dd / ((double)NB * (double)CHW) + R / (double)NB);
    }
}

extern "C" void kernel_launch(void* const* d_in, const int* in_sizes, int n_in,
                              void* d_out, int out_size, void* d_ws, size_t ws_size,
                              hipStream_t stream) {
    const float* mo  = (const float*)d_in[0];
    const float* tg  = (const float*)d_in[1];
    const float* x0  = (const float*)d_in[2];
    const float* var = (const float*)d_in[3];
    float* out = (float*)d_out;

    float* ws_r = (float*)d_ws;            // 2*NB floats
    float* ws_d = ws_r + 2 * NB;           // 2*NB floats

    darcy_wave_kernel<<<NB / 2, 256, 0, stream>>>(mo, tg, x0, ws_r, ws_d);
    darcy_final_kernel<<<1, 256, 0, stream>>>(ws_r, ws_d, var, out);
}

// Round 14
// 75.000 us; speedup vs baseline: 5.5193x; 3.8455x over previous
//
#include <hip/hip_runtime.h>

// DarcyLoss: B=4096, C=2, H=W=64. Inputs (f32): model_out, target, x0_hat [B,2,64,64], var [B].
// loss = mean((mo-tg)^2) + mean_b( min(0.5*r_b^2/var_b, 27.6310211159) )
// r_b = (sum(eq0)+sum(bc)) / (64*64*3);  source f_s sums to 0 -> omitted.
//
// R14: async global_load_lds double-buffer. Block (4 waves) handles 2 batches:
//   stage(buf0) -> barrier -> stage(buf1, async) -> compute(b0) -> barrier -> compute(b1)
// Staging: 8 x global_load_lds (16B/lane) per batch = 32 KB burst, zero VGPR cost,
// drained by __syncthreads. Compute: R8's proven scalar stencil from LDS
// (lane j = column j, wave w owns rows 16w..16w+15, halos read from LDS),
// mo/tg via R6's proven deep nt-streaming block (16 vf4 issued up front/wave).
// Per-wave partials to ws (4 per batch), combined before square/clamp in final.

#define NB 4096
#define HW 4096          // 64*64
#define CHW 8192         // 2*64*64

typedef float vf4 __attribute__((ext_vector_type(4)));

__device__ __forceinline__ void hderiv2(float v, int j, float& d1, float& d11) {
    constexpr float INV2D = 31.5f, INVD2 = 3969.0f;
    float vm = __shfl(v, (j + 63) & 63);
    float vp = __shfl(v, (j + 1) & 63);
    float v2 = __shfl(v, (j == 0) ? 2 : 61);
    float v3 = __shfl(v, (j == 0) ? 3 : 60);
    d1  = (vp - vm) * INV2D;
    d11 = (vp - 2.0f * v + vm) * INVD2;
    if (j == 0)  { d1 = (-3.0f * v + 4.0f * vp - v2) * INV2D;
                   d11 = (2.0f * v - 5.0f * vp + 4.0f * v2 - v3) * INVD2; }
    if (j == 63) { d1 = ( 3.0f * v - 4.0f * vm + v2) * INV2D;
                   d11 = (2.0f * v - 5.0f * vm + 4.0f * v2 - v3) * INVD2; }
}

__device__ __forceinline__ float hderiv1(float v, int j) {
    constexpr float INV2D = 31.5f;
    float vm = __shfl(v, (j + 63) & 63);
    float vp = __shfl(v, (j + 1) & 63);
    float v2 = __shfl(v, (j == 0) ? 2 : 61);
    float d = (vp - vm) * INV2D;
    if (j == 0)  d = (-3.0f * v + 4.0f * vp - v2) * INV2D;
    if (j == 63) d = ( 3.0f * v - 4.0f * vm + v2) * INV2D;
    return d;
}

// Stage one batch's x0 (8192 floats = 32 KB) into LDS.
// Mapping: float k of the batch -> lds[k]. Round r moves floats [r*1024, r*1024+1024).
__device__ __forceinline__ void stage_batch(const float* __restrict__ gsrc,
                                            float* __restrict__ ldst,
                                            int tid, int wv) {
#if defined(__has_builtin) && __has_builtin(__builtin_amdgcn_global_load_lds)
    #pragma unroll
    for (int r = 0; r < 8; ++r) {
        const float* g = gsrc + (r << 10) + (tid << 2);     // per-lane source
        float*       l = ldst + (r << 10) + (wv << 8);      // wave-uniform dest base
        __builtin_amdgcn_global_load_lds(
            (const __attribute__((address_space(1))) void*)g,
            (__attribute__((address_space(3))) void*)l, 16, 0, 0);
    }
#else
    #pragma unroll
    for (int r = 0; r < 8; ++r)
        *(vf4*)(ldst + (r << 10) + (tid << 2)) =
            *(const vf4*)(gsrc + (r << 10) + (tid << 2));
#endif
}

__device__ __forceinline__ void compute_batch(
    const float* __restrict__ sb,               // LDS: p[4096] then q[4096]
    const float* __restrict__ mo, const float* __restrict__ tg,
    int b, int wv, int j,
    float* __restrict__ ws_r, float* __restrict__ ws_d)
{
    constexpr float INV2D = 31.5f, INVD2 = 3969.0f;
    const float* sp = sb;
    const float* sq = sb + HW;
    const vf4* m4 = (const vf4*)(mo + (size_t)b * CHW);     // 2048 f4
    const vf4* g4 = (const vf4*)(tg + (size_t)b * CHW);

    // ---- deep nt streaming first: 16 vf4 issued up front (R6-proven codegen) ----
    const int cbase = wv << 3;                  // wave w: chunks 8w..8w+7
    float a0 = 0.f, a1 = 0.f, a2 = 0.f, a3 = 0.f;
    #pragma unroll
    for (int cc = 0; cc < 8; ++cc) {
        vf4 a = __builtin_nontemporal_load(m4 + ((cbase + cc) << 6) + j);
        vf4 g = __builtin_nontemporal_load(g4 + ((cbase + cc) << 6) + j);
        vf4 e = a - g;
        a0 += e.x * e.x; a1 += e.y * e.y; a2 += e.z * e.z; a3 += e.w * e.w;
    }
    float dsum = (a0 + a1) + (a2 + a3);
    float rsum = 0.f;

    // ---- stencil: wave w owns rows 16w..16w+15; halos read from LDS ----
    const int r0 = wv << 4;
    const int ca = (wv == 0) ? 1 : r0;          // central range [ca, cb]
    const int cb = (wv == 3) ? 62 : (r0 + 15);

    if (wv == 0) {      // row 0 one-sided (rows 0..3)
        float pd1, pd11;
        hderiv2(sp[j], j, pd1, pd11);
        float qd1 = hderiv1(sq[j], j);
        float pd0  = (-3.f * sp[j] + 4.f * sp[64 + j] - sp[128 + j]) * INV2D;
        float pd00 = (2.f * sp[j] - 5.f * sp[64 + j] + 4.f * sp[128 + j] - sp[192 + j]) * INVD2;
        float qd0  = (-3.f * sq[j] + 4.f * sq[64 + j] - sq[128 + j]) * INV2D;
        rsum += -sq[j] * (pd00 + pd11) - qd0 * pd0 - qd1 * pd1 - pd0;   // bc(i=0)
        rsum += (j == 0) ? pd1 : 0.f;
        rsum -= (j == 63) ? pd1 : 0.f;
    }

    float pm = sp[(ca - 1) * 64 + j], pc = sp[ca * 64 + j];
    float qm = sq[(ca - 1) * 64 + j], qc = sq[ca * 64 + j];

    #pragma unroll 4
    for (int i = ca; i <= cb; ++i) {
        float pp = sp[(i + 1) * 64 + j];
        float qp = sq[(i + 1) * 64 + j];

        float pd1, pd11;
        hderiv2(pc, j, pd1, pd11);
        float qd1 = hderiv1(qc, j);
        float pd0  = (pp - pm) * INV2D;
        float pd00 = (pp - 2.f * pc + pm) * INVD2;
        float qd0  = (qp - qm) * INV2D;
        rsum += -qc * (pd00 + pd11) - qd0 * pd0 - qd1 * pd1;
        rsum += (j == 0) ? pd1 : 0.f;
        rsum -= (j == 63) ? pd1 : 0.f;

        pm = pc; pc = pp; qm = qc; qc = qp;
    }

    if (wv == 3) {      // row 63 one-sided (rows 60..63)
        float pd1, pd11;
        hderiv2(sp[63 * 64 + j], j, pd1, pd11);
        float qd1 = hderiv1(sq[63 * 64 + j], j);
        float pd0  = (3.f * sp[63 * 64 + j] - 4.f * sp[62 * 64 + j] + sp[61 * 64 + j]) * INV2D;
        float pd00 = (2.f * sp[63 * 64 + j] - 5.f * sp[62 * 64 + j]
                      + 4.f * sp[61 * 64 + j] - sp[60 * 64 + j]) * INVD2;
        float qd0  = (3.f * sq[63 * 64 + j] - 4.f * sq[62 * 64 + j] + sq[61 * 64 + j]) * INV2D;
        rsum += -sq[63 * 64 + j] * (pd00 + pd11) - qd0 * pd0 - qd1 * pd1 + pd0;   // bc(i=63)
        rsum += (j == 0) ? pd1 : 0.f;
        rsum -= (j == 63) ? pd1 : 0.f;
    }

    // ---- per-wave reduction; 4 partials per batch ----
    #pragma unroll
    for (int off = 32; off > 0; off >>= 1) {
        rsum += __shfl_down(rsum, off);
        dsum += __shfl_down(dsum, off);
    }
    if (j == 0) {
        ws_r[wv * NB + b] = rsum;
        ws_d[wv * NB + b] = dsum;
    }
}

__global__ __launch_bounds__(256, 2) void darcy_lds_kernel(
    const float* __restrict__ mo, const float* __restrict__ tg,
    const float* __restrict__ x0,
    float* __restrict__ ws_r, float* __restrict__ ws_d)
{
    __shared__ float sbuf[2][CHW];              // 2 x 32 KB = 64 KB

    const int tid = threadIdx.x;
    const int wv  = tid >> 6;
    const int j   = tid & 63;
    const int b0  = blockIdx.x * 2;

    stage_batch(x0 + (size_t)b0 * CHW, sbuf[0], tid, wv);
    __syncthreads();                            // drains gld_lds -> buf0 ready

    stage_batch(x0 + (size_t)(b0 + 1) * CHW, sbuf[1], tid, wv);  // async under compute
    compute_batch(sbuf[0], mo, tg, b0, wv, j, ws_r, ws_d);
    __syncthreads();                            // drains -> buf1 ready

    compute_batch(sbuf[1], mo, tg, b0 + 1, wv, j, ws_r, ws_d);
}

__global__ __launch_bounds__(256) void darcy_final_kernel(
    const float* __restrict__ ws_r, const float* __restrict__ ws_d,
    const float* __restrict__ var, float* __restrict__ out)
{
    constexpr float CLAMP = 27.6310211159f;
    const int t = threadIdx.x;
    double rs = 0.0, ds = 0.0;
    for (int i = t; i < NB; i += 256) {
        const float rb = ws_r[i] + ws_r[NB + i] + ws_r[2 * NB + i] + ws_r[3 * NB + i];
        const float db = ws_d[i] + ws_d[NB + i] + ws_d[2 * NB + i] + ws_d[3 * NB + i];
        const float r  = rb * (1.0f / (64.0f * 64.0f * 3.0f));
        float res = 0.5f * r * r / var[i];
        rs += (double)fminf(res, CLAMP);
        ds += (double)db;
    }
    #pragma unroll
    for (int off = 32; off > 0; off >>= 1) {
        rs += __shfl_down(rs, off);
        ds += __shfl_down(ds, off);
    }
    __shared__ double red[8];
    const int wid = t >> 6, lane = t & 63;
    if (lane == 0) { red[wid] = rs; red[4 + wid] = ds; }
    __syncthreads();
    if (t == 0) {
        const double R  = red[0] + red[1] + red[2] + red[3];
        const double Dd = red[4] + red[5] + red[6] + red[7];
        out[0] = (float)(Dd / ((double)NB * (double)CHW) + R / (double)NB);
    }
}

extern "C" void kernel_launch(void* const* d_in, const int* in_sizes, int n_in,
                              void* d_out, int out_size, void* d_ws, size_t ws_size,
                              hipStream_t stream) {
    const float* mo  = (const float*)d_in[0];
    const float* tg  = (const float*)d_in[1];
    const float* x0  = (const float*)d_in[2];
    const float* var = (const float*)d_in[3];
    float* out = (float*)d_out;

    float* ws_r = (float*)d_ws;            // 4*NB floats
    float* ws_d = ws_r + 4 * NB;           // 4*NB floats

    darcy_lds_kernel<<<NB / 2, 256, 0, stream>>>(mo, tg, x0, ws_r, ws_d);
    darcy_final_kernel<<<1, 256, 0, stream>>>(ws_r, ws_d, var, out);
}